// Round 1
// baseline (98.365 us; speedup 1.0000x reference)
//
#include <hip/hip_runtime.h>
#include <math.h>

// BispectrumCalculator:
//   y = fft(target)  [B,T,N] complex
//   Bx[k,l] = y[k] * conj(y[l]) * y[(l-k) mod N]
//   source = stack([Bx.re, Bx.im], ch).mean(T)  -> [B, 2, N, N]
//   outputs: (source, target)  -> d_out = source flat (16,777,216) ++ target flat (65,536)

#define NN 512
#define TT 4
#define BB 32

// ---------------------------------------------------------------------------
// Kernel A: naive DFT-512 per (b,t). 512 blocks x 128 threads; each block
// covers one quarter of the k-range for one (b,t). x[n] reads are
// wave-uniform -> scalar loads. Twiddles via 4 independent complex rotors
// (no LDS table -> no bank conflicts, ILP across the serial rotation chain).
// ---------------------------------------------------------------------------
__global__ __launch_bounds__(128) void dft_kernel(const float* __restrict__ x,
                                                  float2* __restrict__ y) {
    int bt = blockIdx.x >> 2;
    int k  = ((blockIdx.x & 3) << 7) | threadIdx.x;
    const float* xp = x + (size_t)bt * NN;

    float ang = -2.0f * (float)M_PI * (float)k / (float)NN;

    // rotors w[j] = exp(i*ang*j), advanced by exp(i*ang*4) each group of 4
    float2 w0, w1, w2, w3;
    float s4, c4;
    w0 = make_float2(1.0f, 0.0f);
    sincosf(ang,        &w1.y, &w1.x);
    sincosf(2.0f * ang, &w2.y, &w2.x);
    sincosf(3.0f * ang, &w3.y, &w3.x);
    sincosf(4.0f * ang, &s4,   &c4);

    float2 a0 = make_float2(0.f, 0.f), a1 = a0, a2 = a0, a3 = a0;

    #pragma unroll 4
    for (int n = 0; n < NN; n += 4) {
        float x0 = xp[n];
        float x1 = xp[n + 1];
        float x2 = xp[n + 2];
        float x3 = xp[n + 3];
        a0.x += x0 * w0.x; a0.y += x0 * w0.y;
        a1.x += x1 * w1.x; a1.y += x1 * w1.y;
        a2.x += x2 * w2.x; a2.y += x2 * w2.y;
        a3.x += x3 * w3.x; a3.y += x3 * w3.y;
        float t;
        t = w0.x * c4 - w0.y * s4; w0.y = w0.x * s4 + w0.y * c4; w0.x = t;
        t = w1.x * c4 - w1.y * s4; w1.y = w1.x * s4 + w1.y * c4; w1.x = t;
        t = w2.x * c4 - w2.y * s4; w2.y = w2.x * s4 + w2.y * c4; w2.x = t;
        t = w3.x * c4 - w3.y * s4; w3.y = w3.x * s4 + w3.y * c4; w3.x = t;
    }

    float re = (a0.x + a1.x) + (a2.x + a3.x);
    float im = (a0.y + a1.y) + (a2.y + a3.y);
    y[(size_t)bt * NN + k] = make_float2(re, im);
}

// ---------------------------------------------------------------------------
// Kernel B: bispectrum. Grid = B * 64 blocks of 256 threads.
// Each block: one b, 8 consecutive k-rows. y[b] (16 KiB) staged in LDS.
// Thread owns an l-pair (l0 = 2*tid) -> float2 coalesced stores.
// ---------------------------------------------------------------------------
__global__ __launch_bounds__(256) void bispec_kernel(const float2* __restrict__ y,
                                                     float* __restrict__ out) {
    __shared__ float2 ys[TT * NN];  // 16 KiB

    int b     = blockIdx.x >> 6;
    int kbase = (blockIdx.x & 63) << 3;

    // stage y[b] -> LDS (1024 float4 with 256 threads)
    const float4* src = (const float4*)(y + (size_t)b * TT * NN);
    float4* dst = (float4*)ys;
    #pragma unroll
    for (int i = 0; i < 4; ++i)
        dst[threadIdx.x + 256 * i] = src[threadIdx.x + 256 * i];
    __syncthreads();

    int l0 = threadIdx.x << 1;

    // preload conj-target values for both l (k-invariant)
    float2 bv0[TT], bv1[TT];
    #pragma unroll
    for (int t = 0; t < TT; ++t) {
        bv0[t] = ys[t * NN + l0];
        bv1[t] = ys[t * NN + l0 + 1];
    }

    #pragma unroll
    for (int kk = 0; kk < 8; ++kk) {
        int k = kbase + kk;
        float r0 = 0.f, i0 = 0.f, r1 = 0.f, i1 = 0.f;
        #pragma unroll
        for (int t = 0; t < TT; ++t) {
            float2 a  = ys[t * NN + k];                              // broadcast
            float2 c0 = ys[t * NN + ((l0 - k) & (NN - 1))];
            float2 c1 = ys[t * NN + ((l0 + 1 - k) & (NN - 1))];
            // p = a * conj(bv)
            float pr = a.x * bv0[t].x + a.y * bv0[t].y;
            float pi = a.y * bv0[t].x - a.x * bv0[t].y;
            r0 += pr * c0.x - pi * c0.y;
            i0 += pr * c0.y + pi * c0.x;
            float qr = a.x * bv1[t].x + a.y * bv1[t].y;
            float qi = a.y * bv1[t].x - a.x * bv1[t].y;
            r1 += qr * c1.x - qi * c1.y;
            i1 += qr * c1.y + qi * c1.x;
        }
        size_t base0 = (((size_t)b * 2 + 0) * NN + k) * NN + l0;
        size_t base1 = (((size_t)b * 2 + 1) * NN + k) * NN + l0;
        *(float2*)(out + base0) = make_float2(r0 * 0.25f, r1 * 0.25f);  // real ch
        *(float2*)(out + base1) = make_float2(i0 * 0.25f, i1 * 0.25f);  // imag ch
    }
}

extern "C" void kernel_launch(void* const* d_in, const int* in_sizes, int n_in,
                              void* d_out, int out_size, void* d_ws, size_t ws_size,
                              hipStream_t stream) {
    const float* target = (const float*)d_in[0];
    float* out = (float*)d_out;
    // workspace: y spectrum, B*T*N complex64 = 512 KiB
    float2* y = (float2*)d_ws;

    dft_kernel<<<BB * TT * 4, 128, 0, stream>>>(target, y);
    bispec_kernel<<<BB * 64, 256, 0, stream>>>(y, out);

    // second tuple output: target passthrough
    hipMemcpyAsync(out + (size_t)BB * 2 * NN * NN, target,
                   (size_t)BB * TT * NN * sizeof(float),
                   hipMemcpyDeviceToDevice, stream);
}